// Round 1
// baseline (5437.555 us; speedup 1.0000x reference)
//
#include <hip/hip_runtime.h>

// ---------------- problem constants ----------------
#define CDIM   512
#define NTOK   4096          // 16*16*16
#define TOT    (CDIM*NTOK)   // 2097152
#define NHEADS 8
#define HD     64
#define MLPD   4096
#define EPS    1e-5f
#define ATT_SCALE 0.125f     // 64^-0.5

// =====================================================================
// GroupNorm(1,C): global mean/var over all C*N elements, then affine.
// Two-stage deterministic reduction.
// =====================================================================
__global__ __launch_bounds__(256) void gn_reduce1(const float* __restrict__ x,
                                                  float* __restrict__ part) {
  int idx = blockIdx.x * 256 + threadIdx.x;      // float4 index
  const float4* x4 = (const float4*)x;
  float s = 0.f, q = 0.f;
#pragma unroll
  for (int it = 0; it < 2; ++it) {
    float4 v = x4[idx + it * 262144];            // TOT/4/2 = 262144
    s += (v.x + v.y) + (v.z + v.w);
    q += (v.x * v.x + v.y * v.y) + (v.z * v.z + v.w * v.w);
  }
#pragma unroll
  for (int off = 32; off > 0; off >>= 1) {
    s += __shfl_down(s, off);
    q += __shfl_down(q, off);
  }
  __shared__ float ls[4], lq[4];
  int lane = threadIdx.x & 63, w = threadIdx.x >> 6;
  if (lane == 0) { ls[w] = s; lq[w] = q; }
  __syncthreads();
  if (threadIdx.x == 0) {
    part[2 * blockIdx.x]     = (ls[0] + ls[1]) + (ls[2] + ls[3]);
    part[2 * blockIdx.x + 1] = (lq[0] + lq[1]) + (lq[2] + lq[3]);
  }
}

__global__ __launch_bounds__(1024) void gn_reduce2(const float* __restrict__ part,
                                                   float* __restrict__ stats) {
  __shared__ float ss[1024], sq[1024];
  int t = threadIdx.x;
  ss[t] = part[2 * t];
  sq[t] = part[2 * t + 1];
  __syncthreads();
  for (int off = 512; off > 0; off >>= 1) {
    if (t < off) { ss[t] += ss[t + off]; sq[t] += sq[t + off]; }
    __syncthreads();
  }
  if (t == 0) {
    float inv = 1.f / (float)TOT;
    float mu = ss[0] * inv;
    float var = sq[0] * inv - mu * mu;
    stats[0] = mu;
    stats[1] = rsqrtf(var + EPS);
  }
}

__global__ __launch_bounds__(256) void gn_apply(const float* __restrict__ x,
                                                const float* __restrict__ stats,
                                                const float* __restrict__ g,
                                                const float* __restrict__ b,
                                                float* __restrict__ out) {
  int i = blockIdx.x * 256 + threadIdx.x;        // float4 index, 0..524287
  float mu = stats[0], rs = stats[1];
  int c = i >> 10;                               // NTOK/4 = 1024 float4 per row
  float gc = g[c] * rs;
  float bc = b[c] - mu * gc;
  float4 v = ((const float4*)x)[i];
  float4 o;
  o.x = v.x * gc + bc; o.y = v.y * gc + bc;
  o.z = v.z * gc + bc; o.w = v.w * gc + bc;
  ((float4*)out)[i] = o;
}

// =====================================================================
// Tiled fp32 SGEMM: C[M,N] = A[M,K] * B[K,N] (+bias) (+relu | +residual)
// MODE: 0 = store, 2 = bias+relu store, 3 = bias + accumulate into Cio
// =====================================================================
template <int BM, int BN, int TM, int TN, int MODE>
__global__ __launch_bounds__(256) void sgemm_k(const float* __restrict__ A,
                                               const float* __restrict__ B,
                                               const float* __restrict__ bias,
                                               float* __restrict__ Cio,
                                               int M, int N, int K) {
  constexpr int BK = 16;
  constexpr int PAD = 4;
  __shared__ float As[BK][BM + PAD];   // transposed A tile
  __shared__ float Bs[BK][BN];

  const int tid = threadIdx.x;
  const int tx = tid % (BN / TN);
  const int ty = tid / (BN / TN);
  const int m0 = blockIdx.y * BM;
  const int n0 = blockIdx.x * BN;

  float acc[TM][TN] = {};

  constexpr int A_LOADS = BM * BK / (256 * 4);
  constexpr int B_LOADS = BK * BN / (256 * 4);

  for (int k0 = 0; k0 < K; k0 += BK) {
#pragma unroll
    for (int p = 0; p < A_LOADS; ++p) {
      int flat = p * 256 + tid;                 // float4 id in BM x BK tile
      int row = flat >> 2;                      // BK/4 = 4 quads per row
      int q = flat & 3;
      float4 v = *(const float4*)&A[(m0 + row) * K + k0 + q * 4];
      As[q * 4 + 0][row] = v.x;
      As[q * 4 + 1][row] = v.y;
      As[q * 4 + 2][row] = v.z;
      As[q * 4 + 3][row] = v.w;
    }
#pragma unroll
    for (int p = 0; p < B_LOADS; ++p) {
      int flat = p * 256 + tid;                 // float4 id in BK x BN tile
      int row = flat / (BN / 4);
      int q = flat % (BN / 4);
      *(float4*)&Bs[row][q * 4] = *(const float4*)&B[(k0 + row) * N + n0 + q * 4];
    }
    __syncthreads();
#pragma unroll
    for (int kk = 0; kk < BK; ++kk) {
      float a[TM], b[TN];
#pragma unroll
      for (int i = 0; i < TM; i += 4)
        *(float4*)&a[i] = *(const float4*)&As[kk][ty * TM + i];
#pragma unroll
      for (int j = 0; j < TN; j += 4)
        *(float4*)&b[j] = *(const float4*)&Bs[kk][tx * TN + j];
#pragma unroll
      for (int i = 0; i < TM; ++i)
#pragma unroll
        for (int j = 0; j < TN; ++j)
          acc[i][j] += a[i] * b[j];
    }
    __syncthreads();
  }

#pragma unroll
  for (int i = 0; i < TM; ++i) {
    int m = m0 + ty * TM + i;
    float bi = 0.f;
    if constexpr (MODE > 0) bi = bias[m];
#pragma unroll
    for (int j = 0; j < TN; j += 4) {
      int n = n0 + tx * TN + j;
      float4 r;
      r.x = acc[i][j + 0] + bi;
      r.y = acc[i][j + 1] + bi;
      r.z = acc[i][j + 2] + bi;
      r.w = acc[i][j + 3] + bi;
      if constexpr (MODE == 2) {
        r.x = fmaxf(r.x, 0.f); r.y = fmaxf(r.y, 0.f);
        r.z = fmaxf(r.z, 0.f); r.w = fmaxf(r.w, 0.f);
      }
      if constexpr (MODE == 3) {
        float4 cprev = *(const float4*)&Cio[m * N + n];
        r.x += cprev.x; r.y += cprev.y; r.z += cprev.z; r.w += cprev.w;
      }
      *(float4*)&Cio[m * N + n] = r;
    }
  }
}

// =====================================================================
// Flash attention, fp32. Layout: q/k/v are [512][N] where channel
// index = c*8 + h  (C split as (head_dim, heads) per the reference).
// Block: one (head, 64-query tile). 256 threads, 16x16 map, 4x4 micro.
// =====================================================================
__global__ __launch_bounds__(256) void attn_k(const float* __restrict__ Q,
                                              const float* __restrict__ K,
                                              const float* __restrict__ V,
                                              float* __restrict__ O) {
  __shared__ float Qs[64][68];   // [c][qi]
  __shared__ float Ks[64][68];   // [c][ki]
  __shared__ float Vs[64][68];   // [ki][c]   (transposed at load)
  __shared__ float Ps[64][68];   // [qi][ki]

  const int tid = threadIdx.x;
  const int tx = tid & 15, ty = tid >> 4;
  const int h = blockIdx.y;
  const int q0 = blockIdx.x * 64;

  // load Q tile (coalesced along tokens)
#pragma unroll
  for (int p = 0; p < 4; ++p) {
    int flat = p * 256 + tid;            // 64 rows x 16 float4
    int row = flat >> 4, q = flat & 15;
    *(float4*)&Qs[row][q * 4] =
        *(const float4*)&Q[(row * 8 + h) * NTOK + q0 + q * 4];
  }

  float m_run[4], l_run[4], o_acc[4][4];
#pragma unroll
  for (int i = 0; i < 4; ++i) {
    m_run[i] = -1e30f;
    l_run[i] = 0.f;
#pragma unroll
    for (int j = 0; j < 4; ++j) o_acc[i][j] = 0.f;
  }

  for (int kb = 0; kb < NTOK / 64; ++kb) {
    int k0 = kb * 64;
    __syncthreads();                     // previous iteration fully consumed
#pragma unroll
    for (int p = 0; p < 4; ++p) {
      int flat = p * 256 + tid;
      int row = flat >> 4, q = flat & 15;
      *(float4*)&Ks[row][q * 4] =
          *(const float4*)&K[(row * 8 + h) * NTOK + k0 + q * 4];
      float4 v = *(const float4*)&V[(row * 8 + h) * NTOK + k0 + q * 4];
      Vs[q * 4 + 0][row] = v.x;
      Vs[q * 4 + 1][row] = v.y;
      Vs[q * 4 + 2][row] = v.z;
      Vs[q * 4 + 3][row] = v.w;
    }
    __syncthreads();

    // S = (Q^T K) * scale
    float s[4][4] = {};
    for (int c = 0; c < 64; ++c) {
      float a[4], b[4];
      *(float4*)a = *(const float4*)&Qs[c][ty * 4];
      *(float4*)b = *(const float4*)&Ks[c][tx * 4];
#pragma unroll
      for (int i = 0; i < 4; ++i)
#pragma unroll
        for (int j = 0; j < 4; ++j) s[i][j] += a[i] * b[j];
    }

    // online softmax
    float bm[4];
#pragma unroll
    for (int i = 0; i < 4; ++i) {
      s[i][0] *= ATT_SCALE; s[i][1] *= ATT_SCALE;
      s[i][2] *= ATT_SCALE; s[i][3] *= ATT_SCALE;
      bm[i] = fmaxf(fmaxf(s[i][0], s[i][1]), fmaxf(s[i][2], s[i][3]));
    }
#pragma unroll
    for (int off = 1; off < 16; off <<= 1)
#pragma unroll
      for (int i = 0; i < 4; ++i) bm[i] = fmaxf(bm[i], __shfl_xor(bm[i], off));

    float bs[4];
#pragma unroll
    for (int i = 0; i < 4; ++i) {
      float mn = fmaxf(m_run[i], bm[i]);
      float f = __expf(m_run[i] - mn);
      m_run[i] = mn;
      s[i][0] = __expf(s[i][0] - mn); s[i][1] = __expf(s[i][1] - mn);
      s[i][2] = __expf(s[i][2] - mn); s[i][3] = __expf(s[i][3] - mn);
      bs[i] = (s[i][0] + s[i][1]) + (s[i][2] + s[i][3]);
      l_run[i] = l_run[i] * f;
#pragma unroll
      for (int j = 0; j < 4; ++j) o_acc[i][j] *= f;
    }
#pragma unroll
    for (int off = 1; off < 16; off <<= 1)
#pragma unroll
      for (int i = 0; i < 4; ++i) bs[i] += __shfl_xor(bs[i], off);
#pragma unroll
    for (int i = 0; i < 4; ++i) l_run[i] += bs[i];

    // publish P
#pragma unroll
    for (int i = 0; i < 4; ++i) {
      float4 pv; pv.x = s[i][0]; pv.y = s[i][1]; pv.z = s[i][2]; pv.w = s[i][3];
      *(float4*)&Ps[ty * 4 + i][tx * 4] = pv;
    }
    __syncthreads();

    // O += P * V   (o_acc[i][j]: query ty*4+i, dim tx*4+j)
    for (int kk = 0; kk < 64; ++kk) {
      float b[4];
      *(float4*)b = *(const float4*)&Vs[kk][tx * 4];
#pragma unroll
      for (int i = 0; i < 4; ++i) {
        float a = Ps[ty * 4 + i][kk];
#pragma unroll
        for (int j = 0; j < 4; ++j) o_acc[i][j] += a * b[j];
      }
    }
  }

  // normalize, transpose via LDS (reuse Ks), coalesced store
  __syncthreads();
#pragma unroll
  for (int i = 0; i < 4; ++i) {
    float inv = 1.f / l_run[i];
#pragma unroll
    for (int j = 0; j < 4; ++j) Ks[tx * 4 + j][ty * 4 + i] = o_acc[i][j] * inv;
  }
  __syncthreads();
#pragma unroll
  for (int p = 0; p < 4; ++p) {
    int flat = p * 256 + tid;
    int row = flat >> 4, q = flat & 15;
    *(float4*)&O[(row * 8 + h) * NTOK + q0 + q * 4] = *(const float4*)&Ks[row][q * 4];
  }
}

// =====================================================================
// host-side orchestration
// =====================================================================
extern "C" void kernel_launch(void* const* d_in, const int* in_sizes, int n_in,
                              void* d_out, int out_size, void* d_ws, size_t ws_size,
                              hipStream_t stream) {
  const float* x   = (const float*)d_in[0];
  const float* g1  = (const float*)d_in[1];
  const float* b1  = (const float*)d_in[2];
  const float* g2  = (const float*)d_in[3];
  const float* b2  = (const float*)d_in[4];
  const float* wq  = (const float*)d_in[5];
  const float* wk  = (const float*)d_in[6];
  const float* wv  = (const float*)d_in[7];
  const float* wp  = (const float*)d_in[8];
  const float* bp  = (const float*)d_in[9];
  const float* w1  = (const float*)d_in[10];
  const float* bb1 = (const float*)d_in[11];
  const float* w2  = (const float*)d_in[12];
  const float* bb2 = (const float*)d_in[13];

  float* ws   = (float*)d_ws;
  float* xcur = ws;
  float* xn   = ws + 1 * (size_t)TOT;
  float* qb   = ws + 2 * (size_t)TOT;
  float* kb   = ws + 3 * (size_t)TOT;
  float* vb   = ws + 4 * (size_t)TOT;
  float* hb   = ws + 5 * (size_t)TOT;                 // MLPD*NTOK floats
  float* part = hb + (size_t)MLPD * NTOK;             // 2048 floats
  float* stats = part + 2048;                         // 2 floats

  size_t need_bytes = ((size_t)5 * TOT + (size_t)MLPD * NTOK + 2050) * sizeof(float);
  if (ws_size < need_bytes) return;  // workspace too small: bail (will show as incorrect)

  hipMemcpyAsync(xcur, x, (size_t)TOT * sizeof(float), hipMemcpyDeviceToDevice, stream);

  for (int l = 0; l < 4; ++l) {
    // --- x = x + attn(GN1(x)) ---
    gn_reduce1<<<1024, 256, 0, stream>>>(xcur, part);
    gn_reduce2<<<1, 1024, 0, stream>>>(part, stats);
    gn_apply<<<2048, 256, 0, stream>>>(xcur, stats, g1 + l * CDIM, b1 + l * CDIM, xn);

    sgemm_k<64, 128, 4, 8, 0><<<dim3(32, 8), 256, 0, stream>>>(
        wq + (size_t)l * CDIM * CDIM, xn, nullptr, qb, CDIM, NTOK, CDIM);
    sgemm_k<64, 128, 4, 8, 0><<<dim3(32, 8), 256, 0, stream>>>(
        wk + (size_t)l * CDIM * CDIM, xn, nullptr, kb, CDIM, NTOK, CDIM);
    sgemm_k<64, 128, 4, 8, 0><<<dim3(32, 8), 256, 0, stream>>>(
        wv + (size_t)l * CDIM * CDIM, xn, nullptr, vb, CDIM, NTOK, CDIM);

    attn_k<<<dim3(64, 8), 256, 0, stream>>>(qb, kb, vb, xn);   // xn <- attention out

    sgemm_k<64, 128, 4, 8, 3><<<dim3(32, 8), 256, 0, stream>>>(
        wp + (size_t)l * CDIM * CDIM, xn, bp + l * CDIM, xcur, CDIM, NTOK, CDIM);

    // --- x = x + FFN(GN2(x)) ---
    gn_reduce1<<<1024, 256, 0, stream>>>(xcur, part);
    gn_reduce2<<<1, 1024, 0, stream>>>(part, stats);
    gn_apply<<<2048, 256, 0, stream>>>(xcur, stats, g2 + l * CDIM, b2 + l * CDIM, xn);

    sgemm_k<128, 128, 8, 8, 2><<<dim3(32, 32), 256, 0, stream>>>(
        w1 + (size_t)l * MLPD * CDIM, xn, bb1 + l * MLPD, hb, MLPD, NTOK, CDIM);
    sgemm_k<64, 128, 4, 8, 3><<<dim3(32, 8), 256, 0, stream>>>(
        w2 + (size_t)l * CDIM * MLPD, hb, bb2 + l * CDIM, xcur, CDIM, NTOK, MLPD);
  }

  hipMemcpyAsync(d_out, xcur, (size_t)TOT * sizeof(float), hipMemcpyDeviceToDevice, stream);
}

// Round 5
// 1355.771 us; speedup vs baseline: 4.0107x; 4.0107x over previous
//
#include <hip/hip_runtime.h>

// ---------------- problem constants ----------------
#define CDIM   512
#define NTOK   4096          // 16*16*16
#define TOT    (CDIM*NTOK)   // 2097152
#define NHEADS 8
#define HD     64
#define MLPD   4096
#define EPS    1e-5f
#define ATT_SCALE 0.125f     // 64^-0.5

typedef _Float16 f16;
typedef _Float16 f16x8 __attribute__((ext_vector_type(8)));
typedef float    f32x4 __attribute__((ext_vector_type(4)));

__device__ inline f32x4 zero4() { f32x4 z; z[0]=0.f; z[1]=0.f; z[2]=0.f; z[3]=0.f; return z; }

// =====================================================================
// GroupNorm(1,C) stats: global mean/var over all C*N elems (layout-free)
// =====================================================================
__global__ __launch_bounds__(256) void gn_reduce1(const float* __restrict__ x,
                                                  float* __restrict__ part) {
  int idx = blockIdx.x * 256 + threadIdx.x;      // float4 index
  const float4* x4 = (const float4*)x;
  float s = 0.f, q = 0.f;
#pragma unroll
  for (int it = 0; it < 2; ++it) {
    float4 v = x4[idx + it * 262144];            // TOT/4/2 = 262144
    s += (v.x + v.y) + (v.z + v.w);
    q += (v.x * v.x + v.y * v.y) + (v.z * v.z + v.w * v.w);
  }
#pragma unroll
  for (int off = 32; off > 0; off >>= 1) {
    s += __shfl_down(s, off);
    q += __shfl_down(q, off);
  }
  __shared__ float ls[4], lq[4];
  int lane = threadIdx.x & 63, w = threadIdx.x >> 6;
  if (lane == 0) { ls[w] = s; lq[w] = q; }
  __syncthreads();
  if (threadIdx.x == 0) {
    part[2 * blockIdx.x]     = (ls[0] + ls[1]) + (ls[2] + ls[3]);
    part[2 * blockIdx.x + 1] = (lq[0] + lq[1]) + (lq[2] + lq[3]);
  }
}

__global__ __launch_bounds__(1024) void gn_reduce2(const float* __restrict__ part,
                                                   float* __restrict__ stats) {
  __shared__ float ss[1024], sq[1024];
  int t = threadIdx.x;
  ss[t] = part[2 * t];
  sq[t] = part[2 * t + 1];
  __syncthreads();
  for (int off = 512; off > 0; off >>= 1) {
    if (t < off) { ss[t] += ss[t + off]; sq[t] += sq[t + off]; }
    __syncthreads();
  }
  if (t == 0) {
    float inv = 1.f / (float)TOT;
    float mu = ss[0] * inv;
    float var = sq[0] * inv - mu * mu;
    stats[0] = mu;
    stats[1] = rsqrtf(var + EPS);
  }
}

// GN apply on token-major fp32 x -> token-major f16 out
__global__ __launch_bounds__(256) void gn_apply_f16(const float* __restrict__ x,
                                                    const float* __restrict__ stats,
                                                    const float* __restrict__ g,
                                                    const float* __restrict__ b,
                                                    f16* __restrict__ out) {
  int i = blockIdx.x * 256 + threadIdx.x;        // 8-elem unit, 0..262143
  float mu = stats[0], rs = stats[1];
  int c0 = (i & 63) * 8;                         // 512 ch per row, 64 chunks
  const float4* x4 = (const float4*)x;
  float4 a = x4[i * 2], c = x4[i * 2 + 1];
  float4 G0 = *(const float4*)(g + c0);
  float4 G1 = *(const float4*)(g + c0 + 4);
  float4 B0 = *(const float4*)(b + c0);
  float4 B1 = *(const float4*)(b + c0 + 4);
  f16x8 o;
  o[0] = (f16)((a.x - mu) * rs * G0.x + B0.x);
  o[1] = (f16)((a.y - mu) * rs * G0.y + B0.y);
  o[2] = (f16)((a.z - mu) * rs * G0.z + B0.z);
  o[3] = (f16)((a.w - mu) * rs * G0.w + B0.w);
  o[4] = (f16)((c.x - mu) * rs * G1.x + B1.x);
  o[5] = (f16)((c.y - mu) * rs * G1.y + B1.y);
  o[6] = (f16)((c.z - mu) * rs * G1.z + B1.z);
  o[7] = (f16)((c.w - mu) * rs * G1.w + B1.w);
  *(f16x8*)&out[(size_t)i * 8] = o;
}

// =====================================================================
// fp32 tiled transpose: dst[c][r] = src[r][c]; src is [R][C]
// grid: dim3(C/64, R/64)
// =====================================================================
__global__ __launch_bounds__(256) void transpose_f32(const float* __restrict__ src,
                                                     float* __restrict__ dst,
                                                     int R, int C) {
  __shared__ float t[64][65];
  int c0 = blockIdx.x * 64, r0 = blockIdx.y * 64;
  for (int id = threadIdx.x; id < 1024; id += 256) {
    int row = id >> 4, cc = id & 15;
    *(float4*)&t[row][cc * 4] = *(const float4*)&src[(size_t)(r0 + row) * C + c0 + cc * 4];
  }
  __syncthreads();
  for (int id = threadIdx.x; id < 1024; id += 256) {
    int row = id >> 4, cc = id & 15;               // row: c-local, cc: r chunk
    float4 o;
    o.x = t[cc * 4 + 0][row];
    o.y = t[cc * 4 + 1][row];
    o.z = t[cc * 4 + 2][row];
    o.w = t[cc * 4 + 3][row];
    *(float4*)&dst[(size_t)(c0 + row) * R + r0 + cc * 4] = o;
  }
}

// =====================================================================
// fp32 -> f16 weight conversion with per-layer destination strides.
// element e: layer l = e >> shift, rem r = e & ((1<<shift)-1);
// dst[l*dstride + doff + r] = (f16)src[e]
// =====================================================================
__global__ __launch_bounds__(256) void cvt_f16(const float* __restrict__ src,
                                               f16* __restrict__ dst,
                                               int shift, int dstride, int doff,
                                               int total8) {
  int i = blockIdx.x * 256 + threadIdx.x;        // 8-elem unit
  if (i >= total8) return;
  size_t e = (size_t)i * 8;
  int l = (int)(e >> shift);
  int r = (int)(e & (((size_t)1 << shift) - 1));
  float4 a = *(const float4*)(src + e);
  float4 c = *(const float4*)(src + e + 4);
  f16x8 o;
  o[0] = (f16)a.x; o[1] = (f16)a.y; o[2] = (f16)a.z; o[3] = (f16)a.w;
  o[4] = (f16)c.x; o[5] = (f16)c.y; o[6] = (f16)c.z; o[7] = (f16)c.w;
  *(f16x8*)&dst[(size_t)l * dstride + doff + r] = o;
}

// =====================================================================
// MFMA f16 GEMM: C[m][n] = sum_k A[m][k] * Bw[n][k]   (A:[4096][K], Bw:[N][K])
// BM=128, BK=64, 4 waves (2x2), wave tile 64 x (BN/2).
// MODE 0: f16 store; 1: +bias, relu, f16 store; 2: fp32 accumulate += acc+bias
// =====================================================================
template <int BN, int MODE>
__global__ __launch_bounds__(256) void hgemm(const f16* __restrict__ A,
                                             const f16* __restrict__ Bw,
                                             const float* __restrict__ bias,
                                             f16* __restrict__ Cf16,
                                             float* __restrict__ Cf32,
                                             int N, int K) {
  constexpr int WN = BN / 2;
  constexpr int NB = WN / 16;
  __shared__ f16 As[128][72];   // +16B pad: conflict-free ds_read_b128
  __shared__ f16 Bs[BN][72];

  const int tid = threadIdx.x;
  const int lane = tid & 63, wid = tid >> 6;
  const int wm = wid >> 1, wn = wid & 1;
  const int m0 = blockIdx.y * 128, n0 = blockIdx.x * BN;
  const int l15 = lane & 15, hi = lane >> 4;

  f32x4 acc[4][NB];
#pragma unroll
  for (int mb = 0; mb < 4; ++mb)
#pragma unroll
    for (int nb = 0; nb < NB; ++nb) acc[mb][nb] = zero4();

  for (int k0 = 0; k0 < K; k0 += 64) {
#pragma unroll
    for (int p = 0; p < 4; ++p) {
      int id = p * 256 + tid;
      int row = id >> 3, cc = id & 7;
      *(f16x8*)&As[row][cc * 8] = *(const f16x8*)&A[(size_t)(m0 + row) * K + k0 + cc * 8];
    }
#pragma unroll
    for (int p = 0; p < BN / 32; ++p) {
      int id = p * 256 + tid;
      int row = id >> 3, cc = id & 7;
      *(f16x8*)&Bs[row][cc * 8] = *(const f16x8*)&Bw[(size_t)(n0 + row) * K + k0 + cc * 8];
    }
    __syncthreads();
#pragma unroll
    for (int ks = 0; ks < 2; ++ks) {
      f16x8 af[4], bf[NB];
#pragma unroll
      for (int mb = 0; mb < 4; ++mb)
        af[mb] = *(const f16x8*)&As[wm * 64 + mb * 16 + l15][ks * 32 + hi * 8];
#pragma unroll
      for (int nb = 0; nb < NB; ++nb)
        bf[nb] = *(const f16x8*)&Bs[wn * WN + nb * 16 + l15][ks * 32 + hi * 8];
#pragma unroll
      for (int mb = 0; mb < 4; ++mb)
#pragma unroll
        for (int nb = 0; nb < NB; ++nb)
          acc[mb][nb] = __builtin_amdgcn_mfma_f32_16x16x32_f16(af[mb], bf[nb], acc[mb][nb], 0, 0, 0);
    }
    __syncthreads();
  }

  const int rbase = m0 + wm * 64 + hi * 4;
#pragma unroll
  for (int mb = 0; mb < 4; ++mb) {
#pragma unroll
    for (int nb = 0; nb < NB; ++nb) {
      int col = n0 + wn * WN + nb * 16 + l15;
      float bv = 0.f;
      if constexpr (MODE >= 1) bv = bias[col];
#pragma unroll
      for (int r = 0; r < 4; ++r) {
        int row = rbase + mb * 16 + r;
        float v = acc[mb][nb][r];
        if constexpr (MODE == 0) {
          Cf16[(size_t)row * N + col] = (f16)v;
        } else if constexpr (MODE == 1) {
          v += bv;
          v = fmaxf(v, 0.f);
          Cf16[(size_t)row * N + col] = (f16)v;
        } else {
          Cf32[(size_t)row * N + col] += v + bv;
        }
      }
    }
  }
}

// =====================================================================
// permute QKV: qkv[tok][1536] -> qh[h][tok][hd] (q, pre-scaled), kh likewise
// =====================================================================
__global__ __launch_bounds__(256) void perm_qk(const f16* __restrict__ qkv,
                                               f16* __restrict__ qh,
                                               f16* __restrict__ kh) {
  int g = blockIdx.x * 256 + threadIdx.x;        // 0..262143
  int hd0 = (g & 7) * 8;
  int tok = (g >> 3) & 4095;
  int h = g >> 15;
  const f16* row = qkv + (size_t)tok * 1536;
  f16x8 qo, ko;
#pragma unroll
  for (int u = 0; u < 8; ++u) {
    int c = (hd0 + u) * 8 + h;
    qo[u] = (f16)((float)row[c] * ATT_SCALE);    // fold softmax scale into Q (exact)
    ko[u] = row[512 + c];
  }
  size_t o = ((size_t)h * NTOK + tok) * 64 + hd0;
  *(f16x8*)&qh[o] = qo;
  *(f16x8*)&kh[o] = ko;
}

// permute V: vc[c][tok] = qkv[tok][1024+c]  (tiled transpose)
__global__ __launch_bounds__(256) void perm_v(const f16* __restrict__ qkv,
                                              f16* __restrict__ vc) {
  __shared__ f16 t[64][72];
  int t0 = blockIdx.x * 64, c0 = blockIdx.y * 64;
  for (int id = threadIdx.x; id < 512; id += 256) {
    int row = id >> 3, cc = id & 7;
    *(f16x8*)&t[row][cc * 8] = *(const f16x8*)&qkv[(size_t)(t0 + row) * 1536 + 1024 + c0 + cc * 8];
  }
  __syncthreads();
  for (int id = threadIdx.x; id < 512; id += 256) {
    int row = id >> 3, cc = id & 7;               // row: c-local, cc: tok chunk
    f16x8 o;
#pragma unroll
    for (int u = 0; u < 8; ++u) o[u] = t[cc * 8 + u][row];
    *(f16x8*)&vc[(size_t)(c0 + row) * NTOK + t0 + cc * 8] = o;
  }
}

// =====================================================================
// MFMA f16 flash attention. qh/kh: [8][4096][64] (q pre-scaled),
// vc: [512][4096] channel-major (channel = hd*8+h), out ot: [4096][512].
// Block: (q-tile of 64, head). 4 waves; wave w owns 16-query strip.
// =====================================================================
__global__ __launch_bounds__(256) void attn_f16(const f16* __restrict__ qh,
                                                const f16* __restrict__ kh,
                                                const f16* __restrict__ vc,
                                                f16* __restrict__ ot) {
  __shared__ f16 Qs[64][72];
  __shared__ f16 Ks[128][72];
  __shared__ f16 Vs[64][136];    // [hd][kt]
  __shared__ f16 Ps[64][136];    // [qi][kt]

  const int tid = threadIdx.x;
  const int lane = tid & 63, w = tid >> 6;
  const int l15 = lane & 15, hi = lane >> 4;
  const int h = blockIdx.y, q0 = blockIdx.x * 64;

  for (int id = tid; id < 512; id += 256) {
    int row = id >> 3, cc = id & 7;
    *(f16x8*)&Qs[row][cc * 8] =
        *(const f16x8*)&qh[((size_t)h * NTOK + q0 + row) * 64 + cc * 8];
  }
  __syncthreads();

  f16x8 qf[2];
#pragma unroll
  for (int ks = 0; ks < 2; ++ks)
    qf[ks] = *(const f16x8*)&Qs[w * 16 + l15][ks * 32 + hi * 8];

  float m_run[4], l_run[4];
  f32x4 oacc[4];
#pragma unroll
  for (int r = 0; r < 4; ++r) { m_run[r] = -1e30f; l_run[r] = 0.f; }
#pragma unroll
  for (int nbh = 0; nbh < 4; ++nbh) oacc[nbh] = zero4();

  for (int kb = 0; kb < NTOK / 128; ++kb) {
    int k0 = kb * 128;
    __syncthreads();   // prev iter's reads of Ks/Vs done
    for (int id = tid; id < 1024; id += 256) {
      int row = id >> 3, cc = id & 7;
      *(f16x8*)&Ks[row][cc * 8] =
          *(const f16x8*)&kh[((size_t)h * NTOK + k0 + row) * 64 + cc * 8];
    }
    for (int id = tid; id < 1024; id += 256) {
      int row = id >> 4, cc = id & 15;            // row = hd, cc = kt chunk
      *(f16x8*)&Vs[row][cc * 8] =
          *(const f16x8*)&vc[(size_t)(row * 8 + h) * NTOK + k0 + cc * 8];
    }
    __syncthreads();

    // S (pre-scaled) for this wave's 16-query strip x 128 keys
    f32x4 sacc[8];
#pragma unroll
    for (int nb = 0; nb < 8; ++nb) sacc[nb] = zero4();
#pragma unroll
    for (int ks = 0; ks < 2; ++ks) {
      f16x8 qq = qf[ks];
#pragma unroll
      for (int nb = 0; nb < 8; ++nb) {
        f16x8 kf = *(const f16x8*)&Ks[nb * 16 + l15][ks * 32 + hi * 8];
        sacc[nb] = __builtin_amdgcn_mfma_f32_16x16x32_f16(qq, kf, sacc[nb], 0, 0, 0);
      }
    }

    // online softmax (rows r: qi = w*16 + hi*4 + r; cols: ki = l15 + 16*nb)
#pragma unroll
    for (int r = 0; r < 4; ++r) {
      float mx = sacc[0][r];
#pragma unroll
      for (int nb = 1; nb < 8; ++nb) mx = fmaxf(mx, sacc[nb][r]);
#pragma unroll
      for (int off = 1; off < 16; off <<= 1) mx = fmaxf(mx, __shfl_xor(mx, off));
      float mnew = fmaxf(m_run[r], mx);
      float fs = __expf(m_run[r] - mnew);
      m_run[r] = mnew;
      int prow = w * 16 + hi * 4 + r;
      float ps = 0.f;
#pragma unroll
      for (int nb = 0; nb < 8; ++nb) {
        float p = __expf(sacc[nb][r] - mnew);
        ps += p;
        Ps[prow][nb * 16 + l15] = (f16)p;
      }
#pragma unroll
      for (int off = 1; off < 16; off <<= 1) ps += __shfl_xor(ps, off);
      l_run[r] = l_run[r] * fs + ps;
#pragma unroll
      for (int nbh = 0; nbh < 4; ++nbh) oacc[nbh][r] *= fs;
    }
    // P rows are wave-private; same-wave LDS RAW is ordered by lgkmcnt.

    // O += P * V
#pragma unroll
    for (int ks = 0; ks < 4; ++ks) {
      f16x8 pf = *(const f16x8*)&Ps[w * 16 + l15][ks * 32 + hi * 8];
#pragma unroll
      for (int nbh = 0; nbh < 4; ++nbh) {
        f16x8 vf = *(const f16x8*)&Vs[nbh * 16 + l15][ks * 32 + hi * 8];
        oacc[nbh] = __builtin_amdgcn_mfma_f32_16x16x32_f16(pf, vf, oacc[nbh], 0, 0, 0);
      }
    }
  }

  // normalize + store: channel = hd*8 + h
#pragma unroll
  for (int r = 0; r < 4; ++r) {
    float inv = 1.f / l_run[r];
    int row = q0 + w * 16 + hi * 4 + r;
#pragma unroll
    for (int nbh = 0; nbh < 4; ++nbh) {
      int hd = nbh * 16 + l15;
      ot[(size_t)row * 512 + hd * 8 + h] = (f16)(oacc[nbh][r] * inv);
    }
  }
}

// =====================================================================
// host-side orchestration
// =====================================================================
extern "C" void kernel_launch(void* const* d_in, const int* in_sizes, int n_in,
                              void* d_out, int out_size, void* d_ws, size_t ws_size,
                              hipStream_t stream) {
  const float* x   = (const float*)d_in[0];
  const float* g1  = (const float*)d_in[1];
  const float* b1  = (const float*)d_in[2];
  const float* g2  = (const float*)d_in[3];
  const float* b2  = (const float*)d_in[4];
  const float* wq  = (const float*)d_in[5];
  const float* wk  = (const float*)d_in[6];
  const float* wv  = (const float*)d_in[7];
  const float* wp  = (const float*)d_in[8];
  const float* bp  = (const float*)d_in[9];
  const float* w1  = (const float*)d_in[10];
  const float* bb1 = (const float*)d_in[11];
  const float* w2  = (const float*)d_in[12];
  const float* bb2 = (const float*)d_in[13];

  char* base = (char*)d_ws;
  size_t off = 0;
  f16* wqkvF = (f16*)(base + off); off += (size_t)4 * 786432 * 2;    // 6291456
  f16* wpF   = (f16*)(base + off); off += (size_t)4 * 262144 * 2;    // 2097152
  f16* w1F   = (f16*)(base + off); off += (size_t)4 * 2097152 * 2;   // 16777216
  f16* w2F   = (f16*)(base + off); off += (size_t)4 * 2097152 * 2;   // 16777216
  float* xcur = (float*)(base + off); off += (size_t)TOT * 4;        // 8388608
  f16* xnT   = (f16*)(base + off); off += (size_t)TOT * 2;           // 4194304
  float* part = (float*)(base + off);
  float* stats = part + 2048;
  off += 8704;
  char* U = base + off; off += 33554432;                             // union region
  f16* qkvT = (f16*)U;
  f16* qh   = (f16*)(U + 12582912);
  f16* kh   = (f16*)(U + 16777216);
  f16* vcm  = (f16*)(U + 20971520);
  f16* oT   = (f16*)(U + 25165824);
  f16* hT   = (f16*)U;

  if (ws_size < off) return;   // need ~88.1 MB

  // weights -> f16 (every launch; no persistent state)
  cvt_f16<<<512, 256, 0, stream>>>(wq, wqkvF, 18, 786432, 0, 131072);
  cvt_f16<<<512, 256, 0, stream>>>(wk, wqkvF, 18, 786432, 262144, 131072);
  cvt_f16<<<512, 256, 0, stream>>>(wv, wqkvF, 18, 786432, 524288, 131072);
  cvt_f16<<<512, 256, 0, stream>>>(wp, wpF, 18, 262144, 0, 131072);
  cvt_f16<<<4096, 256, 0, stream>>>(w1, w1F, 21, 2097152, 0, 1048576);
  cvt_f16<<<4096, 256, 0, stream>>>(w2, w2F, 21, 2097152, 0, 1048576);

  // x [512][4096] -> xcur token-major [4096][512]
  transpose_f32<<<dim3(64, 8), 256, 0, stream>>>(x, xcur, 512, 4096);

  for (int l = 0; l < 4; ++l) {
    // --- x = x + attn(GN1(x)) ---
    gn_reduce1<<<1024, 256, 0, stream>>>(xcur, part);
    gn_reduce2<<<1, 1024, 0, stream>>>(part, stats);
    gn_apply_f16<<<1024, 256, 0, stream>>>(xcur, stats, g1 + l * CDIM, b1 + l * CDIM, xnT);

    hgemm<128, 0><<<dim3(12, 32), 256, 0, stream>>>(
        xnT, wqkvF + (size_t)l * 786432, nullptr, qkvT, nullptr, 1536, 512);
    perm_qk<<<1024, 256, 0, stream>>>(qkvT, qh, kh);
    perm_v<<<dim3(64, 8), 256, 0, stream>>>(qkvT, vcm);
    attn_f16<<<dim3(64, 8), 256, 0, stream>>>(qh, kh, vcm, oT);
    hgemm<64, 2><<<dim3(8, 32), 256, 0, stream>>>(
        oT, wpF + (size_t)l * 262144, bp + l * CDIM, nullptr, xcur, 512, 512);

    // --- x = x + FFN(GN2(x)) ---
    gn_reduce1<<<1024, 256, 0, stream>>>(xcur, part);
    gn_reduce2<<<1, 1024, 0, stream>>>(part, stats);
    gn_apply_f16<<<1024, 256, 0, stream>>>(xcur, stats, g2 + l * CDIM, b2 + l * CDIM, xnT);

    hgemm<128, 1><<<dim3(32, 32), 256, 0, stream>>>(
        xnT, w1F + (size_t)l * 2097152, bb1 + l * MLPD, hT, nullptr, 4096, 512);
    hgemm<64, 2><<<dim3(8, 32), 256, 0, stream>>>(
        hT, w2F + (size_t)l * 2097152, bb2 + l * CDIM, nullptr, xcur, 512, 4096);
  }

  // xcur [4096][512] -> d_out [512][4096]
  transpose_f32<<<dim3(8, 64), 256, 0, stream>>>(xcur, (float*)d_out, 4096, 512);
}